// Round 3
// baseline (338.729 us; speedup 1.0000x reference)
//
#include <hip/hip_runtime.h>

// MeanSquaredError3: heatmap MSE (d1) + offset-regression MSE (d2), scalar out.
//
// Round 3: depth-4 software pipeline on the h stream. Round 2 kept only one
// 784B h-load in flight per wave (~12 KB/CU duty-cycled) vs the ~22 KB/CU
// needed to saturate HBM at ~900cyc latency -> ~4x off roofline. A rotating
// buf[4] keeps 3 loads in flight per wave (75 KB/CU) while the argmax/tt
// compute of the current pair runs. t/v batched across lanes (1 round trip),
// ox/oy gathers deferred and batched after the loop. Deterministic per-block
// partials (no atomics/memset) -> 256-thread finish kernel.

#define COL 14
#define NJ 14
#define CELLS (COL * COL)     // 196
#define THREADS 256
#define WPB (THREADS / 64)    // 4 waves per block
#define BLOCKS 2048           // 8192 waves = 32/CU; 114688 pairs -> 14 per wave
#define MAXI 16               // max pairs per wave per super-iteration (<= 64)
#define PFD 4                 // h-stream prefetch depth
#define NEGINF -3.402823466e38f

__global__ __launch_bounds__(THREADS)
void mse3_main(const float* __restrict__ outp, const float* __restrict__ tp,
               const float* __restrict__ vp, double* __restrict__ partial, int npair)
{
    __shared__ float Gs[CELLS];
    __shared__ float cminS[COL], cmaxS[COL];
    __shared__ double part[WPB][4];

    const int tid = threadIdx.x;

    // Build G exactly like the reference: w = exp(-0.5*k^2) fp64, normalized,
    // symmetric-padded identity convolution, accumulated fp64, cast to f32.
    if (tid < CELLS) {
        const double wraw[9] = {3.3546262790251185e-4, 1.1108996538242306e-2,
                                1.353352832366127e-1,  6.065306597126334e-1, 1.0,
                                6.065306597126334e-1,  1.353352832366127e-1,
                                1.1108996538242306e-2, 3.3546262790251185e-4};
        const double Z = 2.5066208042307818;  // sum of wraw
        int gi = tid / COL;
        int gj = tid - COL * gi;
        double a = 0.0;
#pragma unroll
        for (int k = 0; k < 9; ++k) {
            int r = gi + k;  // row into symmetric-padded eye (22 rows)
            int m = (r < 4) ? (3 - r) : ((r < 18) ? (r - 4) : (31 - r));
            if (m == gj) a += wraw[k] / Z;
        }
        Gs[tid] = (float)a;
    }
    __syncthreads();
    // Per-column min/max (all G entries > 0: outer-product min/max factorize;
    // fp multiply is monotone, so factored fp32 min/max == elementwise).
    if (tid < COL) {
        float mn = Gs[tid], mx = mn;
        for (int r = 1; r < COL; ++r) {
            float g = Gs[r * COL + tid];
            mn = fminf(mn, g);
            mx = fmaxf(mx, g);
        }
        cminS[tid] = mn;
        cmaxS[tid] = mx;
    }
    __syncthreads();

    const int lane   = tid & 63;
    const int wv     = tid >> 6;
    const int gwave  = blockIdx.x * WPB + wv;
    const int nwaves = BLOCKS * WPB;

    float s1 = 0.0f, s2 = 0.0f, cnt = 0.0f, n2 = 0.0f;

    for (int pbase = gwave; pbase < npair; pbase += nwaves * MAXI) {
        const int m = min(MAXI, (npair - pbase + nwaves - 1) / nwaves);

        // --- phase 0: batched t/v loads, one pair per lane ---
        int packreg = 0;
        float tvx = 0.f, tvy = 0.f, vvx = 0.f, vvy = 0.f;
        if (lane < m) {
            int p = pbase + lane * nwaves;
            float2 tv = reinterpret_cast<const float2*>(tp)[p];
            float2 vv = reinterpret_cast<const float2*>(vp)[p];
            tvx = tv.x; tvy = tv.y; vvx = vv.x; vvy = vv.y;
            int xi = (int)(tv.x * 14.0f);   // trunc toward 0, as astype(int32)
            int yi = (int)(tv.y * 14.0f);
            bool inb    = (xi >= 0) && (xi <= COL - 1) && (yi >= 0) && (yi <= COL - 1);
            bool vis    = ((int)vv.x == 1);
            bool scat   = vis && inb;
            bool zeroed = vis && !inb;
            float ve0   = zeroed ? 0.0f : vv.x;
            bool vise   = ((int)ve0 == 1);
            int xic = min(max(xi, 0), COL - 1);
            int yic = min(max(yi, 0), COL - 1);
            packreg = xic | (yic << 4) | (scat ? 256 : 0) | (vise ? 512 : 0)
                          | (zeroed ? 1024 : 0);
        }

        // --- prologue: fill the depth-PFD pipeline with h tiles ---
        float4 buf[PFD];
#pragma unroll
        for (int d = 0; d < PFD; ++d) {
            buf[d] = make_float4(0.f, 0.f, 0.f, 0.f);
            if (d < m && lane < 49) {
                int p = pbase + d * nwaves;
                int b = p / NJ, j = p - NJ * b;
                buf[d] = reinterpret_cast<const float4*>(
                    outp + ((size_t)b * (3 * NJ) + j) * CELLS)[lane];
            }
        }

        int myidx = 0;  // lane i keeps argmax idx of its pair i
        for (int ibase = 0; ibase < m; ibase += PFD) {
#pragma unroll
            for (int d = 0; d < PFD; ++d) {
                const int i = ibase + d;
                if (i < m) {
                    float4 hv = buf[d];  // waits only on this slot's load
                    if (i + PFD < m && lane < 49) {  // refill slot -> pair i+PFD
                        int p = pbase + (i + PFD) * nwaves;
                        int b = p / NJ, j = p - NJ * b;
                        buf[d] = reinterpret_cast<const float4*>(
                            outp + ((size_t)b * (3 * NJ) + j) * CELLS)[lane];
                    }
                    const int pk = __shfl(packreg, i, 64);
                    const int xic = pk & 15;
                    const int yic = (pk >> 4) & 15;
                    const bool scat = (pk & 256) != 0;
                    const bool vise = (pk & 512) != 0;

                    // wave argmax, first-occurrence tie-break
                    float best = NEGINF;
                    int bidx = 0;
                    if (lane < 49) {
                        best = hv.x; bidx = 4 * lane;
                        if (hv.y > best) { best = hv.y; bidx = 4 * lane + 1; }
                        if (hv.z > best) { best = hv.z; bidx = 4 * lane + 2; }
                        if (hv.w > best) { best = hv.w; bidx = 4 * lane + 3; }
                    }
#pragma unroll
                    for (int off = 32; off >= 1; off >>= 1) {
                        float ov = __shfl_down(best, off, 64);
                        int   oi = __shfl_down(bidx, off, 64);
                        if (ov > best || (ov == best && oi < bidx)) { best = ov; bidx = oi; }
                    }
                    const int idxb = __shfl(bidx, 0, 64);
                    if (lane == i) myidx = idxb;

                    // s1 += (h - tt)^2 with row-0 visibility mask
                    if (lane < 49) {
                        float h4[4] = {hv.x, hv.y, hv.z, hv.w};
                        int y = (4 * lane) / COL;
                        int x = 4 * lane - COL * y;
                        if (scat) {
                            float mn  = cminS[yic] * cminS[xic];
                            float mx  = cmaxS[yic] * cmaxS[xic];
                            float inv = 1.0f / (mx - mn);
#pragma unroll
                            for (int c = 0; c < 4; ++c) {
                                float tt = (Gs[y * COL + yic] * Gs[x * COL + xic] - mn) * inv;
                                float dd = h4[c] - tt;
                                if (y == 0 && !vise) dd = 0.0f;
                                s1 += dd * dd;
                                ++x; if (x == COL) { x = 0; ++y; }
                            }
                        } else {
#pragma unroll
                            for (int c = 0; c < 4; ++c) {
                                float dd = h4[c];
                                if (y == 0 && !vise) dd = 0.0f;
                                s1 += dd * dd;
                                ++x; if (x == COL) { x = 0; ++y; }
                            }
                        }
                    }
                }
            }
        }

        // --- phase 2: all ox/oy gathers at once (full MLP, one round trip) ---
        if (lane < m) {
            int p = pbase + lane * nwaves;
            int b = p / NJ, j = p - NJ * b;
            const float* base = outp + (size_t)b * (3 * NJ) * CELLS;
            float ox = base[(size_t)(NJ + j) * CELLS + myidx];
            float oy = base[(size_t)(2 * NJ + j) * CELLS + myidx];
            bool zeroed = (packreg & 1024) != 0;
            bool vise   = (packreg & 512) != 0;
            float ve0 = zeroed ? 0.0f : vvx;
            float ve1 = zeroed ? 0.0f : vvy;
            int yc = myidx / COL;
            int xc = myidx - COL * yc;
            const float SC = (float)(1.0 / 14.0);
            float dx = (ox + (float)xc) * SC - tvx; dx *= ve0;
            float dy = (oy + (float)yc) * SC - tvy; dy *= ve1;
            s2 += dx * dx + dy * dy;
            if (vise) cnt += 1.0f;
            n2 += ve0 + ve1;
        }
    }

    // --- wave -> block reduction, deterministic per-block partials ---
#pragma unroll
    for (int off = 32; off >= 1; off >>= 1) {
        s1  += __shfl_down(s1,  off, 64);
        s2  += __shfl_down(s2,  off, 64);
        cnt += __shfl_down(cnt, off, 64);
        n2  += __shfl_down(n2,  off, 64);
    }
    if (lane == 0) {
        part[wv][0] = (double)s1;
        part[wv][1] = (double)s2;
        part[wv][2] = (double)cnt;
        part[wv][3] = (double)n2;
    }
    __syncthreads();
    if (tid == 0) {
        double a0 = 0, a1 = 0, a2 = 0, a3 = 0;
        for (int i = 0; i < WPB; ++i) {
            a0 += part[i][0]; a1 += part[i][1];
            a2 += part[i][2]; a3 += part[i][3];
        }
        double* o = partial + (size_t)blockIdx.x * 4;
        o[0] = a0; o[1] = a1; o[2] = a2; o[3] = a3;
    }
}

__global__ __launch_bounds__(256)
void mse3_final(const double* __restrict__ partial, float* __restrict__ o)
{
    __shared__ double p2[4][4];
    double a0 = 0, a1 = 0, a2 = 0, a3 = 0;
    for (int b = threadIdx.x; b < BLOCKS; b += 256) {
        const double* q = partial + (size_t)b * 4;
        a0 += q[0]; a1 += q[1]; a2 += q[2]; a3 += q[3];
    }
#pragma unroll
    for (int off = 32; off >= 1; off >>= 1) {
        a0 += __shfl_down(a0, off, 64);
        a1 += __shfl_down(a1, off, 64);
        a2 += __shfl_down(a2, off, 64);
        a3 += __shfl_down(a3, off, 64);
    }
    const int lane = threadIdx.x & 63, wv = threadIdx.x >> 6;
    if (lane == 0) { p2[wv][0] = a0; p2[wv][1] = a1; p2[wv][2] = a2; p2[wv][3] = a3; }
    __syncthreads();
    if (threadIdx.x == 0) {
        double s1 = 0, s2 = 0, cn = 0, nn = 0;
        for (int i = 0; i < 4; ++i) {
            s1 += p2[i][0]; s2 += p2[i][1]; cn += p2[i][2]; nn += p2[i][3];
        }
        o[0] = (float)(s1 / cn + s2 / (0.5 * nn));  // d1 + d2
    }
}

extern "C" void kernel_launch(void* const* d_in, const int* in_sizes, int n_in,
                              void* d_out, int out_size, void* d_ws, size_t ws_size,
                              hipStream_t stream)
{
    const float* outp = (const float*)d_in[0];   // (B, 42, 14, 14) f32
    const float* tp   = (const float*)d_in[1];   // (B, 14, 2) f32
    const float* vp   = (const float*)d_in[2];   // (B, 14, 2) f32
    double* partial = (double*)d_ws;             // BLOCKS*4 doubles = 64 KB

    const int B = in_sizes[0] / (3 * NJ * CELLS);
    const int npair = B * NJ;

    mse3_main<<<BLOCKS, THREADS, 0, stream>>>(outp, tp, vp, partial, npair);
    mse3_final<<<1, 256, 0, stream>>>(partial, (float*)d_out);
}